// Round 5
// baseline (531.912 us; speedup 1.0000x reference)
//
#include <hip/hip_runtime.h>
#include <hip/hip_bf16.h>
#include <hip/hip_fp8.h>

// ---------------------------------------------------------------------------
// GRACE contrastive loss, MI355X.
//  out = mean_k 0.5*(ln d1_k + ln d2_k) - 2*s12[k,k]
// With M=[n1;n2] (24576x256) everything is row sums of exp(M M^T / tau)
// split by j-half, plus diagonal probes.
//
// R5: sim uses MX-scaled MFMA (mfma_scale_f32_16x16x128_f8f6f4, unit e8m0
// scales = 2x the non-scaled fp8 rate, 4x fewer instructions). Normalized
// rows pre-scaled by alpha=sqrt(2*log2 e) so acc = s/tau*log2e feeds exp2
// directly (no per-element multiply); diagonal terms rescale in finalize
// (-2s == -ln2 * acc). B-frag reads are two swizzled ds_read_b128 per frag,
// conflict-free. Keeps XCD-pinned j-chunks + K-half software pipeline.
// ---------------------------------------------------------------------------

#define NROWS 12288
#define TWO_N 24576
#define KDIM 256
#define BM 128
#define BN 128
#define BK 32
#define BJ 128
#define KHALF 128               /* fp8 bytes per K-half */
#define NCHUNK 8
#define JCHUNK (TWO_N / NCHUNK) /* 3072 */
#define JTILES (JCHUNK / BJ)    /* 24 */
#define LOG2E 1.4426950408889634f
#define SIMSCALE 1.6986436f     /* sqrt(2*log2(e)); acc = (1/tau)*log2e*s */
#define LN2F 0.6931471805599453f

#if __has_builtin(__builtin_amdgcn_exp2f)
#define EXP2F(x) __builtin_amdgcn_exp2f(x)
#else
#define EXP2F(x) exp2f(x)
#endif

typedef __bf16 bf16x8 __attribute__((ext_vector_type(8)));
typedef __bf16 bf16x4v __attribute__((ext_vector_type(4)));
typedef float f32x4 __attribute__((ext_vector_type(4)));
typedef int i32x4 __attribute__((ext_vector_type(4)));
typedef int i32x8 __attribute__((ext_vector_type(8)));
typedef unsigned char uchar;

typedef const __attribute__((address_space(1))) void* gptr_t;
typedef __attribute__((address_space(3))) void* lptr_t;

// ======== legacy 128x128 bf16 GEMM core (proj1/proj2 only) ================
__device__ __forceinline__ void stage_slab(const __bf16* g, int row0, int kelem,
                                           __bf16* lds, int w, int l) {
#pragma unroll
  for (int t = 0; t < 2; ++t) {
    int chunk = w * 2 + t;
    int r = chunk * 16 + (l >> 2);
    int c = l & 3;
    int src = c ^ (r & 3);
    const __bf16* ga = g + (size_t)(row0 + r) * KDIM + kelem + src * 8;
    __bf16* la = lds + chunk * 512;
    __builtin_amdgcn_global_load_lds((gptr_t)ga, (lptr_t)la, 16, 0, 0);
  }
}

__device__ __forceinline__ bf16x8 read_frag(const __bf16* lds, int rowbase,
                                            int tile, int l) {
  int r = rowbase + tile * 16 + (l & 15);
  int q = l >> 4;
  int blk = q ^ (r & 3);
  return *(const bf16x8*)(lds + r * 32 + blk * 8);
}

__device__ __forceinline__ void gemm_tile_core(const __bf16* A, int arow0,
                                               const __bf16* B, int brow0,
                                               __bf16* As, __bf16* Bs,
                                               f32x4 (&acc)[4][4], int w, int l) {
  const int warow = (w >> 1) * 64;
  const int wbrow = (w & 1) * 64;
#pragma unroll
  for (int ks = 0; ks < KDIM / BK; ++ks) {
    __syncthreads();
    stage_slab(A, arow0, ks * BK, As, w, l);
    stage_slab(B, brow0, ks * BK, Bs, w, l);
    __syncthreads();
    bf16x8 aF[4], bF[4];
#pragma unroll
    for (int mi = 0; mi < 4; ++mi) aF[mi] = read_frag(As, warow, mi, l);
#pragma unroll
    for (int ni = 0; ni < 4; ++ni) bF[ni] = read_frag(Bs, wbrow, ni, l);
#pragma unroll
    for (int mi = 0; mi < 4; ++mi)
#pragma unroll
      for (int ni = 0; ni < 4; ++ni)
        acc[mi][ni] = __builtin_amdgcn_mfma_f32_16x16x32_bf16(
            aF[mi], bF[ni], acc[mi][ni], 0, 0, 0);
  }
}

// ---------------------------------------------------------------------------
__global__ void cast_kernel(const float* __restrict__ src,
                            __bf16* __restrict__ dst, int n4) {
  int i = blockIdx.x * blockDim.x + threadIdx.x;
  if (i >= n4) return;
  float4 v = *(const float4*)(src + (size_t)i * 4);
  bf16x4v o;
  o[0] = (__bf16)v.x; o[1] = (__bf16)v.y; o[2] = (__bf16)v.z; o[3] = (__bf16)v.w;
  *(bf16x4v*)(dst + (size_t)i * 4) = o;
}

// T = ELU(Z @ W1^T + b1), stored bf16
__global__ __launch_bounds__(256, 2) void proj1_kernel(
    const __bf16* __restrict__ Zb, const __bf16* __restrict__ W1b,
    const float* __restrict__ b1, __bf16* __restrict__ Tb) {
  __shared__ __align__(16) __bf16 As[BM * BK];
  __shared__ __align__(16) __bf16 Bs[BN * BK];
  int w = threadIdx.x >> 6, l = threadIdx.x & 63;
  int i0 = blockIdx.x * BM, j0 = blockIdx.y * BN;
  int warow = (w >> 1) * 64, wbrow = (w & 1) * 64;
  f32x4 acc[4][4] = {};
  gemm_tile_core(Zb, i0, W1b, j0, As, Bs, acc, w, l);
  float bias[4];
#pragma unroll
  for (int ni = 0; ni < 4; ++ni) bias[ni] = b1[j0 + wbrow + ni * 16 + (l & 15)];
#pragma unroll
  for (int mi = 0; mi < 4; ++mi)
#pragma unroll
    for (int ni = 0; ni < 4; ++ni)
#pragma unroll
      for (int v = 0; v < 4; ++v) {
        int row = i0 + warow + mi * 16 + (l >> 4) * 4 + v;
        int col = j0 + wbrow + ni * 16 + (l & 15);
        float x = acc[mi][ni][v] + bias[ni];
        x = x > 0.f ? x : (EXP2F(x * LOG2E) - 1.f);  // ELU
        Tb[(size_t)row * KDIM + col] = (__bf16)x;
      }
}

// H = T @ W2^T + b2 (fp32), plus per-row sum of squares via atomics
__global__ __launch_bounds__(256, 2) void proj2_kernel(
    const __bf16* __restrict__ Tb, const __bf16* __restrict__ W2b,
    const float* __restrict__ b2, float* __restrict__ H,
    float* __restrict__ SS) {
  __shared__ __align__(16) __bf16 As[BM * BK];
  __shared__ __align__(16) __bf16 Bs[BN * BK];
  int w = threadIdx.x >> 6, l = threadIdx.x & 63;
  int i0 = blockIdx.x * BM, j0 = blockIdx.y * BN;
  int warow = (w >> 1) * 64, wbrow = (w & 1) * 64;
  f32x4 acc[4][4] = {};
  gemm_tile_core(Tb, i0, W2b, j0, As, Bs, acc, w, l);
  float bias[4];
#pragma unroll
  for (int ni = 0; ni < 4; ++ni) bias[ni] = b2[j0 + wbrow + ni * 16 + (l & 15)];
  float ss[4][4] = {};
#pragma unroll
  for (int mi = 0; mi < 4; ++mi)
#pragma unroll
    for (int ni = 0; ni < 4; ++ni)
#pragma unroll
      for (int v = 0; v < 4; ++v) {
        int row = i0 + warow + mi * 16 + (l >> 4) * 4 + v;
        int col = j0 + wbrow + ni * 16 + (l & 15);
        float x = acc[mi][ni][v] + bias[ni];
        H[(size_t)row * KDIM + col] = x;
        ss[mi][v] += x * x;
      }
#pragma unroll
  for (int mi = 0; mi < 4; ++mi)
#pragma unroll
    for (int v = 0; v < 4; ++v) {
      float x = ss[mi][v];
      x += __shfl_xor(x, 1, 64);
      x += __shfl_xor(x, 2, 64);
      x += __shfl_xor(x, 4, 64);
      x += __shfl_xor(x, 8, 64);
      if ((l & 15) == 0)
        atomicAdd(&SS[i0 + warow + mi * 16 + (l >> 4) * 4 + v], x);
    }
}

// pack 4 floats -> 4 fp8 e4m3 bytes
__device__ __forceinline__ unsigned int pack4_fp8(float a, float b, float c,
                                                  float d) {
#if __has_builtin(__builtin_amdgcn_cvt_pk_fp8_f32)
  int v = 0;
  v = __builtin_amdgcn_cvt_pk_fp8_f32(a, b, v, false);
  v = __builtin_amdgcn_cvt_pk_fp8_f32(c, d, v, true);
  return (unsigned int)v;
#else
  __hip_fp8_e4m3 qa(a), qb(b), qc(c), qd(d);
  return (unsigned int)qa.__x | ((unsigned int)qb.__x << 8) |
         ((unsigned int)qc.__x << 16) | ((unsigned int)qd.__x << 24);
#endif
}

// Nq = fp8(H * rsqrt(SS[row]) * SIMSCALE) — 8 elements per thread.
// SIMSCALE folds the (1/tau)*log2(e) exponent scale into the data:
// dot(Nq_i, Nq_j) = 2.8854 * cos_ij, so exp2(acc) = exp(cos/tau).
__global__ void norm_kernel(const float* __restrict__ H,
                            const float* __restrict__ SS,
                            uchar* __restrict__ Nq) {
  int i = blockIdx.x * blockDim.x + threadIdx.x;
  size_t idx = (size_t)i * 8;
  if (idx >= (size_t)TWO_N * KDIM) return;
  int row = (int)(idx >> 8);
  float inv = rsqrtf(SS[row]) * SIMSCALE;
  float4 h0 = *(const float4*)(H + idx);
  float4 h1 = *(const float4*)(H + idx + 4);
  uint2 o;
  o.x = pack4_fp8(h0.x * inv, h0.y * inv, h0.z * inv, h0.w * inv);
  o.y = pack4_fp8(h1.x * inv, h1.y * inv, h1.z * inv, h1.w * inv);
  *(uint2*)(Nq + idx) = o;
}

// ======== R5 sim kernel (MX-scaled fp8, K=128 per instruction) ============
// grid = 1536 1D blocks. chunk = blockIdx&7 (XCD-pinned), itile = blockIdx>>3.
// 1x4 wave grid: each wave computes all 128 A rows x 32 B cols. A frags in
// 128 VGPRs. B: 128 rows staged per jt in two 16KB K-halves (pipelined);
// frag = two swizzled ds_read_b128 (conflict-free: 8 lanes per 4-bank group).
__global__ __launch_bounds__(256, 2) void sim_kernel(
    const uchar* __restrict__ Nq, float* __restrict__ Rlow,
    float* __restrict__ Rhigh, float* __restrict__ Dsame,
    float* __restrict__ Dcross) {
  __shared__ __align__(16) uchar Bs[2 * BJ * KHALF];  // 2 x 16KB
  int tid = threadIdx.x;
  int w = tid >> 6, l = tid & 63;
  int q = l >> 4;
  int b = blockIdx.x;
  int chunk = b & 7;           // XCD id under round-robin dispatch
  int i0 = (b >> 3) * BM;
  int jbase = chunk * JCHUNK;
  int wbcol = w * 32;          // B cols of this wave: wbcol..wbcol+31

  // stage one 16KB K-half; source-side XOR swizzle (slot c holds global
  // 16B-block c ^ (r&7) of the row-half).
  auto stage_half = [&](int jt, int hf) {
    int j0 = jbase + jt * BJ;
#pragma unroll
    for (int t = 0; t < 4; ++t) {
      int ch = w * 4 + t;            // wave-uniform chunk 0..15 (1KB each)
      int r = ch * 8 + (l >> 3);     // row 0..127 (8 rows per chunk)
      int c = l & 7;                 // dest 16B-block slot
      int src = c ^ (r & 7);         // global k-block landing in slot c
      const uchar* ga = Nq + (size_t)(j0 + r) * KDIM + hf * KHALF + src * 16;
      uchar* la = Bs + hf * (BJ * KHALF) + ch * 1024;  // uniform base
      __builtin_amdgcn_global_load_lds((gptr_t)ga, (lptr_t)la, 16, 0, 0);
    }
  };

  // ---- A fragments in registers: aF[mi][ks], 16 x i32x8 = 128 VGPRs ----
  // f8f6f4 16x16x128 A layout: lane holds row (l&15), k = q*32 + 0..31.
  i32x8 aF[8][2];
#pragma unroll
  for (int mi = 0; mi < 8; ++mi) {
    const uchar* ap = Nq + (size_t)(i0 + mi * 16 + (l & 15)) * KDIM + q * 32;
#pragma unroll
    for (int ks = 0; ks < 2; ++ks)
      aF[mi][ks] = *(const i32x8*)(ap + ks * KHALF);
  }

  float rs[8][4] = {};  // running row sums (per mi, per v)

  stage_half(0, 0);  // prologue: first K-half in flight

  for (int jt = 0; jt < JTILES; ++jt) {
    int j0 = jbase + jt * BJ;
    f32x4 acc[8][2] = {};

    __syncthreads();      // drains half0(jt); half1(jt-1) readers done
    stage_half(jt, 1);    // issue half1(jt) — lands during ks=0 burst

#pragma unroll
    for (int hf = 0; hf < 2; ++hf) {
      i32x8 bF[2];
#pragma unroll
      for (int nj = 0; nj < 2; ++nj) {
        int row = wbcol + nj * 16 + (l & 15);
        const uchar* base = Bs + hf * (BJ * KHALF) + row * KHALF;
        int s_lo = (((2 * q) ^ (row & 7)) << 4);  // slot of global block 2q
        i32x4 lo = *(const i32x4*)(base + s_lo);
        i32x4 hi = *(const i32x4*)(base + (s_lo ^ 16));
        bF[nj] = __builtin_shufflevector(lo, hi, 0, 1, 2, 3, 4, 5, 6, 7);
      }
#pragma unroll
      for (int mi = 0; mi < 8; ++mi)
#pragma unroll
        for (int nj = 0; nj < 2; ++nj)
          acc[mi][nj] = __builtin_amdgcn_mfma_scale_f32_16x16x128_f8f6f4(
              aF[mi][hf], bF[nj], acc[mi][nj], 0, 0, 0, 0x7F7F7F7F, 0,
              0x7F7F7F7F);
      if (hf == 0) {
        __syncthreads();  // drains half1(jt); half0(jt) readers done
        int jn = (jt + 1 < JTILES) ? jt + 1 : jt;
        stage_half(jn, 0);  // half0(jt+1) lands during ks=1 + epilogue
      }
    }

    // epilogue: acc already = s/tau*log2(e); exp2 directly
#pragma unroll
    for (int mi = 0; mi < 8; ++mi)
#pragma unroll
      for (int nj = 0; nj < 2; ++nj)
#pragma unroll
        for (int v = 0; v < 4; ++v)
          rs[mi][v] += EXP2F(acc[mi][nj][v]);

    bool dsame = (j0 == i0);
    bool dcross = (j0 == i0 + NROWS);
    if (dsame | dcross) {       // wave-uniform, 2 of 24 iterations
      float* D = dsame ? Dsame : Dcross;
#pragma unroll
      for (int mi = 0; mi < 8; ++mi)
#pragma unroll
        for (int nj = 0; nj < 2; ++nj)
#pragma unroll
          for (int v = 0; v < 4; ++v) {
            int li = mi * 16 + q * 4 + v;
            int lj = wbcol + nj * 16 + (l & 15);
            if (li == lj) D[i0 + li] = acc[mi][nj][v];
          }
    }
  }

  // cross-lane (16-wide) reduce, one atomicAdd per row per wave
  float* R = (chunk >= NCHUNK / 2) ? Rhigh : Rlow;
#pragma unroll
  for (int mi = 0; mi < 8; ++mi)
#pragma unroll
    for (int v = 0; v < 4; ++v) {
      float x = rs[mi][v];
      x += __shfl_xor(x, 1, 64);
      x += __shfl_xor(x, 2, 64);
      x += __shfl_xor(x, 4, 64);
      x += __shfl_xor(x, 8, 64);
      if ((l & 15) == 0)
        atomicAdd(&R[i0 + mi * 16 + q * 4 + v], x);
    }
}

// Dsame/Dcross hold acc = (1/tau)*log2e * s. exp(s/tau) = exp2(acc);
// -2*s = -ln2 * acc.
__global__ void finalize_kernel(const float* __restrict__ Rlow,
                                const float* __restrict__ Rhigh,
                                const float* __restrict__ Dsame,
                                const float* __restrict__ Dcross,
                                float* __restrict__ out) {
  __shared__ float red[256];
  float acc = 0.f;
  for (int k = threadIdx.x; k < NROWS; k += 256) {
    float d1 = Rlow[k] + Rhigh[k] - EXP2F(Dsame[k]);
    float d2 = Rhigh[NROWS + k] + Rlow[NROWS + k] - EXP2F(Dsame[NROWS + k]);
    acc += 0.5f * (logf(d1) + logf(d2)) - LN2F * Dcross[k];
  }
  red[threadIdx.x] = acc;
  __syncthreads();
  for (int s = 128; s > 0; s >>= 1) {
    if (threadIdx.x < s) red[threadIdx.x] += red[threadIdx.x + s];
    __syncthreads();
  }
  if (threadIdx.x == 0) out[0] = red[0] / (float)NROWS;
}

// ---------------------------------------------------------------------------
extern "C" void kernel_launch(void* const* d_in, const int* in_sizes, int n_in,
                              void* d_out, int out_size, void* d_ws,
                              size_t ws_size, hipStream_t stream) {
  const float* z1 = (const float*)d_in[0];
  const float* z2 = (const float*)d_in[1];
  const float* W1 = (const float*)d_in[2];
  const float* b1 = (const float*)d_in[3];
  const float* W2 = (const float*)d_in[4];
  const float* b2 = (const float*)d_in[5];
  float* out = (float*)d_out;

  char* ws = (char*)d_ws;
  size_t off = 0;
  auto alloc = [&](size_t bytes) -> void* {
    void* p = ws + off;
    off += (bytes + 255) & ~(size_t)255;
    return p;
  };
  __bf16* Zb   = (__bf16*)alloc((size_t)TWO_N * KDIM * 2); // reused as Nq
  __bf16* W1b  = (__bf16*)alloc((size_t)KDIM * KDIM * 2);
  __bf16* W2b  = (__bf16*)alloc((size_t)KDIM * KDIM * 2);
  __bf16* Tb   = (__bf16*)alloc((size_t)TWO_N * KDIM * 2);
  float*  H    = (float*)alloc((size_t)TWO_N * KDIM * 4);
  float*  SS   = (float*)alloc((size_t)TWO_N * 4);
  float*  Rlow = (float*)alloc((size_t)TWO_N * 4);
  float*  Rhigh= (float*)alloc((size_t)TWO_N * 4);
  float*  Dsame= (float*)alloc((size_t)TWO_N * 4);
  float*  Dcross=(float*)alloc((size_t)NROWS * 4);
  uchar*  Nq = (uchar*)Zb;  // Zb dead after proj1; fp8 fits in its footprint

  hipMemsetAsync(SS, 0, (size_t)TWO_N * 4, stream);
  hipMemsetAsync(Rlow, 0, (size_t)TWO_N * 4, stream);
  hipMemsetAsync(Rhigh, 0, (size_t)TWO_N * 4, stream);

  int n4z = NROWS * KDIM / 4;   // 786432
  int n4w = KDIM * KDIM / 4;    // 16384
  cast_kernel<<<(n4z + 255) / 256, 256, 0, stream>>>(z1, Zb, n4z);
  cast_kernel<<<(n4z + 255) / 256, 256, 0, stream>>>(z2, Zb + (size_t)NROWS * KDIM, n4z);
  cast_kernel<<<(n4w + 255) / 256, 256, 0, stream>>>(W1, W1b, n4w);
  cast_kernel<<<(n4w + 255) / 256, 256, 0, stream>>>(W2, W2b, n4w);

  proj1_kernel<<<dim3(TWO_N / BM, KDIM / BN), 256, 0, stream>>>(Zb, W1b, b1, Tb);
  proj2_kernel<<<dim3(TWO_N / BM, KDIM / BN), 256, 0, stream>>>(Tb, W2b, b2, H, SS);

  int n8n = TWO_N * KDIM / 8;   // 786432
  norm_kernel<<<(n8n + 255) / 256, 256, 0, stream>>>(H, SS, Nq);

  sim_kernel<<<(TWO_N / BM) * NCHUNK, 256, 0, stream>>>(Nq, Rlow, Rhigh,
                                                        Dsame, Dcross);
  finalize_kernel<<<1, 256, 0, stream>>>(Rlow, Rhigh, Dsame, Dcross, out);
}

// Round 6
// 282.689 us; speedup vs baseline: 1.8816x; 1.8816x over previous
//
#include <hip/hip_runtime.h>
#include <hip/hip_bf16.h>
#include <hip/hip_fp8.h>

// ---------------------------------------------------------------------------
// GRACE contrastive loss, MI355X.
//  out = mean_k 0.5*(ln d1_k + ln d2_k) - 2*s12[k,k]
// With M=[n1;n2] (24576x256) everything is row sums of exp(M M^T / tau)
// split by j-half, plus diagonal probes.
//
// R6: fix R5's register spilling (FETCH/WRITE +110MB = scratch round-trip).
// sim uses MX-scaled MFMA with a 2x2 wave grid (64x64 per wave): aF 64 regs,
// acc[4] live per nj step only (full-K per nj), bF 8, rs 16 => ~130 regs,
// no spill. jt-level LDS double buffer (2x32KB), ONE barrier per jt; the
// stage(jt+1) issued after barrier(jt) drains at barrier(jt+1), covered by
// 32 MFMAs + exp epilogue. Keeps XCD-pinned j-chunks.
// ---------------------------------------------------------------------------

#define NROWS 12288
#define TWO_N 24576
#define KDIM 256
#define BM 128
#define BN 128
#define BK 32
#define BJ 128
#define NCHUNK 8
#define JCHUNK (TWO_N / NCHUNK) /* 3072 */
#define JTILES (JCHUNK / BJ)    /* 24 */
#define LOG2E 1.4426950408889634f
#define SIMSCALE 1.6986436f     /* sqrt(2*log2(e)); acc = (1/tau)*log2e*s */
#define LN2F 0.6931471805599453f

#if __has_builtin(__builtin_amdgcn_exp2f)
#define EXP2F(x) __builtin_amdgcn_exp2f(x)
#else
#define EXP2F(x) exp2f(x)
#endif

typedef __bf16 bf16x8 __attribute__((ext_vector_type(8)));
typedef __bf16 bf16x4v __attribute__((ext_vector_type(4)));
typedef float f32x4 __attribute__((ext_vector_type(4)));
typedef int i32x4 __attribute__((ext_vector_type(4)));
typedef int i32x8 __attribute__((ext_vector_type(8)));
typedef unsigned char uchar;

typedef const __attribute__((address_space(1))) void* gptr_t;
typedef __attribute__((address_space(3))) void* lptr_t;

// ======== legacy 128x128 bf16 GEMM core (proj1/proj2 only) ================
__device__ __forceinline__ void stage_slab(const __bf16* g, int row0, int kelem,
                                           __bf16* lds, int w, int l) {
#pragma unroll
  for (int t = 0; t < 2; ++t) {
    int chunk = w * 2 + t;
    int r = chunk * 16 + (l >> 2);
    int c = l & 3;
    int src = c ^ (r & 3);
    const __bf16* ga = g + (size_t)(row0 + r) * KDIM + kelem + src * 8;
    __bf16* la = lds + chunk * 512;
    __builtin_amdgcn_global_load_lds((gptr_t)ga, (lptr_t)la, 16, 0, 0);
  }
}

__device__ __forceinline__ bf16x8 read_frag(const __bf16* lds, int rowbase,
                                            int tile, int l) {
  int r = rowbase + tile * 16 + (l & 15);
  int q = l >> 4;
  int blk = q ^ (r & 3);
  return *(const bf16x8*)(lds + r * 32 + blk * 8);
}

__device__ __forceinline__ void gemm_tile_core(const __bf16* A, int arow0,
                                               const __bf16* B, int brow0,
                                               __bf16* As, __bf16* Bs,
                                               f32x4 (&acc)[4][4], int w, int l) {
  const int warow = (w >> 1) * 64;
  const int wbrow = (w & 1) * 64;
#pragma unroll
  for (int ks = 0; ks < KDIM / BK; ++ks) {
    __syncthreads();
    stage_slab(A, arow0, ks * BK, As, w, l);
    stage_slab(B, brow0, ks * BK, Bs, w, l);
    __syncthreads();
    bf16x8 aF[4], bF[4];
#pragma unroll
    for (int mi = 0; mi < 4; ++mi) aF[mi] = read_frag(As, warow, mi, l);
#pragma unroll
    for (int ni = 0; ni < 4; ++ni) bF[ni] = read_frag(Bs, wbrow, ni, l);
#pragma unroll
    for (int mi = 0; mi < 4; ++mi)
#pragma unroll
      for (int ni = 0; ni < 4; ++ni)
        acc[mi][ni] = __builtin_amdgcn_mfma_f32_16x16x32_bf16(
            aF[mi], bF[ni], acc[mi][ni], 0, 0, 0);
  }
}

// ---------------------------------------------------------------------------
__global__ void cast_kernel(const float* __restrict__ src,
                            __bf16* __restrict__ dst, int n4) {
  int i = blockIdx.x * blockDim.x + threadIdx.x;
  if (i >= n4) return;
  float4 v = *(const float4*)(src + (size_t)i * 4);
  bf16x4v o;
  o[0] = (__bf16)v.x; o[1] = (__bf16)v.y; o[2] = (__bf16)v.z; o[3] = (__bf16)v.w;
  *(bf16x4v*)(dst + (size_t)i * 4) = o;
}

// T = ELU(Z @ W1^T + b1), stored bf16
__global__ __launch_bounds__(256, 2) void proj1_kernel(
    const __bf16* __restrict__ Zb, const __bf16* __restrict__ W1b,
    const float* __restrict__ b1, __bf16* __restrict__ Tb) {
  __shared__ __align__(16) __bf16 As[BM * BK];
  __shared__ __align__(16) __bf16 Bs[BN * BK];
  int w = threadIdx.x >> 6, l = threadIdx.x & 63;
  int i0 = blockIdx.x * BM, j0 = blockIdx.y * BN;
  int warow = (w >> 1) * 64, wbrow = (w & 1) * 64;
  f32x4 acc[4][4] = {};
  gemm_tile_core(Zb, i0, W1b, j0, As, Bs, acc, w, l);
  float bias[4];
#pragma unroll
  for (int ni = 0; ni < 4; ++ni) bias[ni] = b1[j0 + wbrow + ni * 16 + (l & 15)];
#pragma unroll
  for (int mi = 0; mi < 4; ++mi)
#pragma unroll
    for (int ni = 0; ni < 4; ++ni)
#pragma unroll
      for (int v = 0; v < 4; ++v) {
        int row = i0 + warow + mi * 16 + (l >> 4) * 4 + v;
        int col = j0 + wbrow + ni * 16 + (l & 15);
        float x = acc[mi][ni][v] + bias[ni];
        x = x > 0.f ? x : (EXP2F(x * LOG2E) - 1.f);  // ELU
        Tb[(size_t)row * KDIM + col] = (__bf16)x;
      }
}

// H = T @ W2^T + b2 (fp32), plus per-row sum of squares via atomics
__global__ __launch_bounds__(256, 2) void proj2_kernel(
    const __bf16* __restrict__ Tb, const __bf16* __restrict__ W2b,
    const float* __restrict__ b2, float* __restrict__ H,
    float* __restrict__ SS) {
  __shared__ __align__(16) __bf16 As[BM * BK];
  __shared__ __align__(16) __bf16 Bs[BN * BK];
  int w = threadIdx.x >> 6, l = threadIdx.x & 63;
  int i0 = blockIdx.x * BM, j0 = blockIdx.y * BN;
  int warow = (w >> 1) * 64, wbrow = (w & 1) * 64;
  f32x4 acc[4][4] = {};
  gemm_tile_core(Tb, i0, W2b, j0, As, Bs, acc, w, l);
  float bias[4];
#pragma unroll
  for (int ni = 0; ni < 4; ++ni) bias[ni] = b2[j0 + wbrow + ni * 16 + (l & 15)];
  float ss[4][4] = {};
#pragma unroll
  for (int mi = 0; mi < 4; ++mi)
#pragma unroll
    for (int ni = 0; ni < 4; ++ni)
#pragma unroll
      for (int v = 0; v < 4; ++v) {
        int row = i0 + warow + mi * 16 + (l >> 4) * 4 + v;
        int col = j0 + wbrow + ni * 16 + (l & 15);
        float x = acc[mi][ni][v] + bias[ni];
        H[(size_t)row * KDIM + col] = x;
        ss[mi][v] += x * x;
      }
#pragma unroll
  for (int mi = 0; mi < 4; ++mi)
#pragma unroll
    for (int v = 0; v < 4; ++v) {
      float x = ss[mi][v];
      x += __shfl_xor(x, 1, 64);
      x += __shfl_xor(x, 2, 64);
      x += __shfl_xor(x, 4, 64);
      x += __shfl_xor(x, 8, 64);
      if ((l & 15) == 0)
        atomicAdd(&SS[i0 + warow + mi * 16 + (l >> 4) * 4 + v], x);
    }
}

// pack 4 floats -> 4 fp8 e4m3 bytes
__device__ __forceinline__ unsigned int pack4_fp8(float a, float b, float c,
                                                  float d) {
#if __has_builtin(__builtin_amdgcn_cvt_pk_fp8_f32)
  int v = 0;
  v = __builtin_amdgcn_cvt_pk_fp8_f32(a, b, v, false);
  v = __builtin_amdgcn_cvt_pk_fp8_f32(c, d, v, true);
  return (unsigned int)v;
#else
  __hip_fp8_e4m3 qa(a), qb(b), qc(c), qd(d);
  return (unsigned int)qa.__x | ((unsigned int)qb.__x << 8) |
         ((unsigned int)qc.__x << 16) | ((unsigned int)qd.__x << 24);
#endif
}

// Nq = fp8(H * rsqrt(SS[row]) * SIMSCALE) — 8 elements per thread.
// SIMSCALE folds the (1/tau)*log2(e) exponent scale into the data:
// dot(Nq_i, Nq_j) = 2.8854 * cos_ij, so exp2(acc) = exp(cos/tau).
__global__ void norm_kernel(const float* __restrict__ H,
                            const float* __restrict__ SS,
                            uchar* __restrict__ Nq) {
  int i = blockIdx.x * blockDim.x + threadIdx.x;
  size_t idx = (size_t)i * 8;
  if (idx >= (size_t)TWO_N * KDIM) return;
  int row = (int)(idx >> 8);
  float inv = rsqrtf(SS[row]) * SIMSCALE;
  float4 h0 = *(const float4*)(H + idx);
  float4 h1 = *(const float4*)(H + idx + 4);
  uint2 o;
  o.x = pack4_fp8(h0.x * inv, h0.y * inv, h0.z * inv, h0.w * inv);
  o.y = pack4_fp8(h1.x * inv, h1.y * inv, h1.z * inv, h1.w * inv);
  *(uint2*)(Nq + idx) = o;
}

// ======== R6 sim kernel (MX-scaled fp8, spill-free) ========================
// grid = 1536 1D blocks. chunk = blockIdx&7 (XCD-pinned), itile = blockIdx>>3.
// 2x2 wave grid (64 rows x 64 cols per wave). aF 64 VGPRs; acc[4] live only
// within one nj step (full-K per nj); jt-level LDS double buffer, one
// barrier per jt.
__global__ __launch_bounds__(256, 2) void sim_kernel(
    const uchar* __restrict__ Nq, float* __restrict__ Rlow,
    float* __restrict__ Rhigh, float* __restrict__ Dsame,
    float* __restrict__ Dcross) {
  __shared__ __align__(16) uchar Bs[2][BJ * KDIM];  // 2 x 32KB
  int tid = threadIdx.x;
  int w = tid >> 6, l = tid & 63;
  int q = l >> 4;
  int b = blockIdx.x;
  int chunk = b & 7;           // XCD id under round-robin dispatch
  int i0 = (b >> 3) * BM;
  int jbase = chunk * JCHUNK;
  int warow = (w >> 1) * 64;   // A rows of this wave
  int wbcol = (w & 1) * 64;    // B cols of this wave

  // stage full 128-row x 256B tile jt into buffer bi; source-side XOR
  // swizzle: LDS slot c of row r holds global 16B-block c ^ (r&15).
  auto stage = [&](int jt, int bi) {
    int j0 = jbase + jt * BJ;
#pragma unroll
    for (int t = 0; t < 8; ++t) {
      int ch = w * 8 + t;            // wave-uniform chunk 0..31 (1KB each)
      int r = ch * 4 + (l >> 4);     // row 0..127 (4 rows per chunk)
      int c = l & 15;                // dest 16B-block slot
      int src = c ^ (r & 15);        // global k-block landing in slot c
      const uchar* ga = Nq + (size_t)(j0 + r) * KDIM + src * 16;
      uchar* la = Bs[bi] + ch * 1024;  // wave-uniform base
      __builtin_amdgcn_global_load_lds((gptr_t)ga, (lptr_t)la, 16, 0, 0);
    }
  };

  // ---- A fragments in registers: aF[mi][hf], 8 x i32x8 = 64 VGPRs ----
  // f8f6f4 16x16x128 A layout: lane holds row (l&15), k = q*32 + 0..31.
  i32x8 aF[4][2];
#pragma unroll
  for (int mi = 0; mi < 4; ++mi) {
    const uchar* ap =
        Nq + (size_t)(i0 + warow + mi * 16 + (l & 15)) * KDIM + q * 32;
#pragma unroll
    for (int hf = 0; hf < 2; ++hf)
      aF[mi][hf] = *(const i32x8*)(ap + hf * 128);
  }

  float rs[4][4] = {};  // running row sums (per mi, per v)

  stage(0, 0);  // prologue

  for (int jt = 0; jt < JTILES; ++jt) {
    int bi = jt & 1;
    __syncthreads();                       // stage(jt) done; prev readers done
    if (jt + 1 < JTILES) stage(jt + 1, bi ^ 1);  // drains at NEXT barrier

    int j0 = jbase + jt * BJ;
    bool dsame = (j0 == i0);
    bool dcross = (j0 == i0 + NROWS);

#pragma unroll
    for (int nj = 0; nj < 4; ++nj) {
      int row = wbcol + nj * 16 + (l & 15);
      const uchar* base = Bs[bi] + row * KDIM;
      f32x4 acc[4] = {};
#pragma unroll
      for (int hf = 0; hf < 2; ++hf) {
        int kb = hf * 8 + 2 * q;                 // even global block index
        int s0 = (kb ^ (row & 15)) << 4;
        i32x4 lo = *(const i32x4*)(base + s0);
        i32x4 hi = *(const i32x4*)(base + (((kb + 1) ^ (row & 15)) << 4));
        i32x8 bF = __builtin_shufflevector(lo, hi, 0, 1, 2, 3, 4, 5, 6, 7);
#pragma unroll
        for (int mi = 0; mi < 4; ++mi)
          acc[mi] = __builtin_amdgcn_mfma_scale_f32_16x16x128_f8f6f4(
              aF[mi][hf], bF, acc[mi], 0, 0, 0, 0x7F7F7F7F, 0, 0x7F7F7F7F);
      }
      // epilogue for this nj: acc = s/tau*log2(e); exp2 directly
#pragma unroll
      for (int mi = 0; mi < 4; ++mi)
#pragma unroll
        for (int v = 0; v < 4; ++v)
          rs[mi][v] += EXP2F(acc[mi][v]);

      if (dsame | dcross) {       // wave-uniform, 2 of 24 jt iterations
        float* D = dsame ? Dsame : Dcross;
#pragma unroll
        for (int mi = 0; mi < 4; ++mi)
#pragma unroll
          for (int v = 0; v < 4; ++v) {
            int li = warow + mi * 16 + q * 4 + v;
            int lj = wbcol + nj * 16 + (l & 15);
            if (li == lj) D[i0 + li] = acc[mi][v];
          }
      }
    }
  }

  // cross-lane (16-wide) reduce, one atomicAdd per row per wave
  float* R = (chunk >= NCHUNK / 2) ? Rhigh : Rlow;
#pragma unroll
  for (int mi = 0; mi < 4; ++mi)
#pragma unroll
    for (int v = 0; v < 4; ++v) {
      float x = rs[mi][v];
      x += __shfl_xor(x, 1, 64);
      x += __shfl_xor(x, 2, 64);
      x += __shfl_xor(x, 4, 64);
      x += __shfl_xor(x, 8, 64);
      if ((l & 15) == 0)
        atomicAdd(&R[i0 + warow + mi * 16 + q * 4 + v], x);
    }
}

// Dsame/Dcross hold acc = (1/tau)*log2e * s. exp(s/tau) = exp2(acc);
// -2*s = -ln2 * acc.
__global__ void finalize_kernel(const float* __restrict__ Rlow,
                                const float* __restrict__ Rhigh,
                                const float* __restrict__ Dsame,
                                const float* __restrict__ Dcross,
                                float* __restrict__ out) {
  __shared__ float red[256];
  float acc = 0.f;
  for (int k = threadIdx.x; k < NROWS; k += 256) {
    float d1 = Rlow[k] + Rhigh[k] - EXP2F(Dsame[k]);
    float d2 = Rhigh[NROWS + k] + Rlow[NROWS + k] - EXP2F(Dsame[NROWS + k]);
    acc += 0.5f * (logf(d1) + logf(d2)) - LN2F * Dcross[k];
  }
  red[threadIdx.x] = acc;
  __syncthreads();
  for (int s = 128; s > 0; s >>= 1) {
    if (threadIdx.x < s) red[threadIdx.x] += red[threadIdx.x + s];
    __syncthreads();
  }
  if (threadIdx.x == 0) out[0] = red[0] / (float)NROWS;
}

// ---------------------------------------------------------------------------
extern "C" void kernel_launch(void* const* d_in, const int* in_sizes, int n_in,
                              void* d_out, int out_size, void* d_ws,
                              size_t ws_size, hipStream_t stream) {
  const float* z1 = (const float*)d_in[0];
  const float* z2 = (const float*)d_in[1];
  const float* W1 = (const float*)d_in[2];
  const float* b1 = (const float*)d_in[3];
  const float* W2 = (const float*)d_in[4];
  const float* b2 = (const float*)d_in[5];
  float* out = (float*)d_out;

  char* ws = (char*)d_ws;
  size_t off = 0;
  auto alloc = [&](size_t bytes) -> void* {
    void* p = ws + off;
    off += (bytes + 255) & ~(size_t)255;
    return p;
  };
  __bf16* Zb   = (__bf16*)alloc((size_t)TWO_N * KDIM * 2); // reused as Nq
  __bf16* W1b  = (__bf16*)alloc((size_t)KDIM * KDIM * 2);
  __bf16* W2b  = (__bf16*)alloc((size_t)KDIM * KDIM * 2);
  __bf16* Tb   = (__bf16*)alloc((size_t)TWO_N * KDIM * 2);
  float*  H    = (float*)alloc((size_t)TWO_N * KDIM * 4);
  float*  SS   = (float*)alloc((size_t)TWO_N * 4);
  float*  Rlow = (float*)alloc((size_t)TWO_N * 4);
  float*  Rhigh= (float*)alloc((size_t)TWO_N * 4);
  float*  Dsame= (float*)alloc((size_t)TWO_N * 4);
  float*  Dcross=(float*)alloc((size_t)NROWS * 4);
  uchar*  Nq = (uchar*)Zb;  // Zb dead after proj1; fp8 fits in its footprint

  hipMemsetAsync(SS, 0, (size_t)TWO_N * 4, stream);
  hipMemsetAsync(Rlow, 0, (size_t)TWO_N * 4, stream);
  hipMemsetAsync(Rhigh, 0, (size_t)TWO_N * 4, stream);

  int n4z = NROWS * KDIM / 4;   // 786432
  int n4w = KDIM * KDIM / 4;    // 16384
  cast_kernel<<<(n4z + 255) / 256, 256, 0, stream>>>(z1, Zb, n4z);
  cast_kernel<<<(n4z + 255) / 256, 256, 0, stream>>>(z2, Zb + (size_t)NROWS * KDIM, n4z);
  cast_kernel<<<(n4w + 255) / 256, 256, 0, stream>>>(W1, W1b, n4w);
  cast_kernel<<<(n4w + 255) / 256, 256, 0, stream>>>(W2, W2b, n4w);

  proj1_kernel<<<dim3(TWO_N / BM, KDIM / BN), 256, 0, stream>>>(Zb, W1b, b1, Tb);
  proj2_kernel<<<dim3(TWO_N / BM, KDIM / BN), 256, 0, stream>>>(Tb, W2b, b2, H, SS);

  int n8n = TWO_N * KDIM / 8;   // 786432
  norm_kernel<<<(n8n + 255) / 256, 256, 0, stream>>>(H, SS, Nq);

  sim_kernel<<<(TWO_N / BM) * NCHUNK, 256, 0, stream>>>(Nq, Rlow, Rhigh,
                                                        Dsame, Dcross);
  finalize_kernel<<<1, 256, 0, stream>>>(Rlow, Rhigh, Dsame, Dcross, out);
}